// Round 6
// baseline (347.773 us; speedup 1.0000x reference)
//
#include <hip/hip_runtime.h>

#define EPS_K 1e-7f

typedef __attribute__((ext_vector_type(8)))  short          frag8;  // 8 bf16
typedef __attribute__((ext_vector_type(16))) float          accf16; // MFMA C/D
typedef __attribute__((ext_vector_type(4)))  unsigned short us4;    // 8B read
typedef __attribute__((ext_vector_type(4)))  float          f32x4;

__device__ __forceinline__ unsigned f2bf(float f) {
  union { float f; unsigned u; } v; v.f = f;
  unsigned u = v.u;
  u += 0x7FFFu + ((u >> 16) & 1u);   // RNE
  return u >> 16;
}
__device__ __forceinline__ float bf2f(unsigned short s) {
  union { unsigned u; float f; } v; v.u = ((unsigned)s) << 16;
  return v.f;
}
__device__ __forceinline__ unsigned pk_bf16(float lo, float hi) {
  return f2bf(lo) | (f2bf(hi) << 16);
}
__device__ __forceinline__ float rcp_f(float x) {
  return __builtin_amdgcn_rcpf(x);   // validated rounds 3/4/5: absmax unchanged
}

// ---------------------------------------------------------------------------
// Pre-pass: W (2048,32,32) f32 [s][t][u] -> Wbf bf16 [s][u][t] (4 MB in ws)
// (verified, unchanged since round 0)
// ---------------------------------------------------------------------------
__global__ __launch_bounds__(256) void wbf_prep(
    const float* __restrict__ Wt, unsigned short* __restrict__ Wbf)
{
  __shared__ unsigned short tile[32 * 33];
  const int s   = blockIdx.x;
  const int tid = threadIdx.x;
  {
    const int t  = tid >> 3;
    const int uc = tid & 7;
    const float4 v = *(const float4*)(Wt + s * 1024 + t * 32 + 4 * uc);
    tile[t * 33 + 4 * uc + 0] = (unsigned short)f2bf(v.x);
    tile[t * 33 + 4 * uc + 1] = (unsigned short)f2bf(v.y);
    tile[t * 33 + 4 * uc + 2] = (unsigned short)f2bf(v.z);
    tile[t * 33 + 4 * uc + 3] = (unsigned short)f2bf(v.w);
  }
  __syncthreads();
  {
    const int u  = tid >> 3;
    const int tc = tid & 7;
    uint2 d;
    d.x = (unsigned)tile[(4 * tc + 0) * 33 + u] | ((unsigned)tile[(4 * tc + 1) * 33 + u] << 16);
    d.y = (unsigned)tile[(4 * tc + 2) * 33 + u] | ((unsigned)tile[(4 * tc + 3) * 33 + u] << 16);
    *(uint2*)(Wbf + s * 1024 + u * 32 + 4 * tc) = d;
  }
}

// ---------------------------------------------------------------------------
// Pass 1 (REWRITTEN): repack x = inp*msk -> Y, bank-conflict-free.
//
// Y layout (VERIFIED by round-5 pass): slice (Q, s) = 512 B; ushort offset
//   = c*64 + slot*8 + j, c = t>>3, j = t&7, slot = b' ^ ((s>>2)&7),
//   b = Q*8 + b'.
//
// New structure: wave = b'. Lane (l5, l31) owns s = 4*l31..+3 and c-groups
// c = 2*c2 + l5 -> it holds ALL 8 t of a slot -> assembles whole 16-B slots
// in registers and writes ds_write_b128 (8 per lane total, was 64 scalar
// b16 at 32-way conflict = round-5's bottleneck).
//
// LDS: 128 rows x 512 B (64 KB), row = s_loc. Row stride 128 dw == 0 mod 32
// -> bank = 4*((slot_id ^ (s_loc&7)) & 7). Write phases: key
// (b7 ^ (l31&7) ^ (4*(l31&1)+k)) hits each bank-group 2x per 16 lanes ->
// 2-way = free (m136). Copy-out un-applies the XOR (2-way) and stores Y as
// a 64-KB contiguous block. Y contents bit-identical to round 5.
//
// Global reads: two 512-B contiguous runs per wave-instr (proven shape).
// ---------------------------------------------------------------------------
__global__ __launch_bounds__(512, 2) void repack(
    const float* __restrict__ inp, const float* __restrict__ msk,
    unsigned short* __restrict__ Y)
{
  __shared__ unsigned short sl[32768];          // 128 rows x 512 B = 64 KB
  const int tid  = threadIdx.x;
  const int lane = tid & 63;
  const int b7   = tid >> 6;                    // wave id = b' 0..7
  const int Q    = blockIdx.x & 63;             // b quarter
  const int w    = blockIdx.x >> 6;             // s-window 0..15
  const int l31  = lane & 31;                   // s-quad index
  const int l5   = lane >> 5;                   // c parity

  const size_t rb = ((size_t)(Q * 8 + b7) * 32 + 8 * l5) * 2048 + w * 128 + 4 * l31;
  const int slot = b7 ^ (l31 & 7);              // == b' ^ ((s>>2)&7) for all 4 k

  #pragma unroll 1
  for (int c2 = 0; c2 < 2; ++c2) {
    f32x4 vi[8], vm[8];
    #pragma unroll
    for (int j = 0; j < 8; ++j) {
      const size_t off = rb + (size_t)(16 * c2 + j) * 2048;  // t = 16c2+8l5+j
      vi[j] = *(const f32x4*)(inp + off);
      vm[j] = *(const f32x4*)(msk + off);
    }
    const int c   = 2 * c2 + l5;
    const int sid = c * 8 + slot;
    #pragma unroll
    for (int k = 0; k < 4; ++k) {
      const int s_loc = 4 * l31 + k;
      uint4 d;
      d.x = pk_bf16(vi[0][k] * vm[0][k], vi[1][k] * vm[1][k]);
      d.y = pk_bf16(vi[2][k] * vm[2][k], vi[3][k] * vm[3][k]);
      d.z = pk_bf16(vi[4][k] * vm[4][k], vi[5][k] * vm[5][k]);
      d.w = pk_bf16(vi[6][k] * vm[6][k], vi[7][k] * vm[7][k]);
      *(uint4*)(sl + s_loc * 256 + ((sid ^ (s_loc & 7)) * 8)) = d;
    }
  }
  __syncthreads();

  const size_t ybyte = ((size_t)Q * 2048 + (size_t)w * 128) * 512;
  #pragma unroll
  for (int i = 0; i < 8; ++i) {
    const int e  = i * 512 + tid;               // 16-B chunk 0..4095
    const int sv = e >> 5, ch = e & 31;
    const uint4 d = *(const uint4*)(sl + sv * 256 + ((ch ^ (sv & 7)) * 8));
    *(uint4*)((char*)Y + ybyte + (size_t)e * 16) = d;
  }
}

// ---------------------------------------------------------------------------
// Pass 2: compute (VERIFIED round 5, unchanged). 1024 blocks x 256 thr.
// MFMA C layout (HW-validated): col = lane&31 = b, row u = (r&3)+8*(r>>2)+4h.
// ---------------------------------------------------------------------------
__global__ __launch_bounds__(256, 4) void attn_comp(
    const unsigned short* __restrict__ Y,
    const unsigned short* __restrict__ Wbf,
    const float* __restrict__ bias,
    float* __restrict__ part)
{
  __shared__ float red[4096];                   // 16 KB epilogue scratch
  const int tid  = threadIdx.x;
  const int bg   = blockIdx.x & 15;
  const int sg   = blockIdx.x >> 4;             // 0..63
  const int lane = tid & 63;
  const int wv   = tid >> 6;
  const int n    = lane & 31;                   // b (B-frag col) / u (A-frag)
  const int h    = lane >> 5;

  const unsigned short* Yq = Y + ((size_t)(bg * 4 + (n >> 3)) * 2048) * 256;

  float O[16];
  #pragma unroll
  for (int r = 0; r < 16; ++r) O[r] = 0.f;

  #pragma unroll 2
  for (int it = 0; it < 8; ++it) {
    const int s = sg * 32 + wv * 8 + it;
    const unsigned short* slp = Yq + (size_t)s * 256;
    const int bt = (((n & 7) ^ ((s >> 2) & 7)) * 8);

    const frag8 b1 = *(const frag8*)(slp + h * 64 + bt);        // t=8h..8h+7
    const frag8 b2 = *(const frag8*)(slp + (h + 2) * 64 + bt);  // +16

    const unsigned short* wp = Wbf + (size_t)s * 1024 + n * 32 + 8 * h;
    const frag8 a1 = *(const frag8*)(wp);
    const frag8 a2 = *(const frag8*)(wp + 16);

    accf16 acc;
    #pragma unroll
    for (int g = 0; g < 4; ++g) {
      const f32x4 bb = *(const f32x4*)(bias + s * 32 + 8 * g + 4 * h);
      acc[4 * g + 0] = bb[0]; acc[4 * g + 1] = bb[1];
      acc[4 * g + 2] = bb[2]; acc[4 * g + 3] = bb[3];
    }
    acc = __builtin_amdgcn_mfma_f32_32x32x16_bf16(a1, b1, acc, 0, 0, 0);
    acc = __builtin_amdgcn_mfma_f32_32x32x16_bf16(a2, b2, acc, 0, 0, 0);

    // e = exp(tanh(z)); tanh(z) = 1 - 2/(exp(2z)+1)
    float ps = 0.f;
    #pragma unroll
    for (int r = 0; r < 16; ++r) {
      const float z  = acc[r];
      const float e2 = __expf(2.f * z);
      const float th = 1.f - 2.f * rcp_f(e2 + 1.f);
      acc[r] = __expf(th);
      ps    += acc[r];
    }
    const float tot = ps + __shfl_xor(ps, 32, 64);
    const float inv = rcp_f(tot + EPS_K);

    #pragma unroll
    for (int g = 0; g < 4; ++g) {
      const us4 xv = *(const us4*)(slp + g * 64 + bt + 4 * h);  // u=8g+4h+i
      #pragma unroll
      for (int i = 0; i < 4; ++i)
        O[4 * g + i] += acc[4 * g + i] * inv * bf2f(xv[i]);
    }
  }

  // ---- cross-wave reduction (verified) ----
  #pragma unroll
  for (int r = 0; r < 16; ++r) {
    const int u = (r & 3) + 8 * (r >> 2) + 4 * h;
    red[wv * 1024 + n * 32 + (u ^ n)] = O[r];
  }
  __syncthreads();

  const int q0 = tid * 4;
  f32x4 v;
  #pragma unroll
  for (int i = 0; i < 4; ++i) {
    const int q = q0 + i;
    const int b = q >> 5, u = q & 31;
    float sum = 0.f;
    #pragma unroll
    for (int w = 0; w < 4; ++w) sum += red[w * 1024 + b * 32 + (u ^ b)];
    v[i] = sum;
  }
  *(f32x4*)(part + (size_t)sg * 16384 + bg * 1024 + q0) = v;
}

// out[f] = sum over 64 s-groups of part[sg][f]
__global__ __launch_bounds__(256) void reduce_part(
    const float* __restrict__ part, float* __restrict__ out)
{
  const int f = blockIdx.x * 256 + threadIdx.x;
  float s = 0.f;
  #pragma unroll 8
  for (int sg = 0; sg < 64; ++sg) s += part[(size_t)sg * 16384 + f];
  out[f] = s;
}

// ---------------------------------------------------------------------------
// Safety fallback (ws too small): correct, slow, f32-precise.
// ---------------------------------------------------------------------------
__global__ __launch_bounds__(256) void attn_naive(
    const float* __restrict__ inp, const float* __restrict__ msk,
    const float* __restrict__ Wt, const float* __restrict__ bias,
    float* __restrict__ out)
{
  const int idx = blockIdx.x * 256 + threadIdx.x;  // 0..16383
  const int b = idx >> 5, sc = idx & 31;
  float O[32];
  #pragma unroll
  for (int u = 0; u < 32; ++u) O[u] = 0.f;
  for (int si = 0; si < 64; ++si) {
    const int s = sc * 64 + si;
    float x[32], z[32];
    for (int t = 0; t < 32; ++t) {
      x[t] = inp[((size_t)b * 32 + t) * 2048 + s] * msk[((size_t)b * 32 + t) * 2048 + s];
      z[t] = bias[s * 32 + t];
    }
    for (int t = 0; t < 32; ++t) {
      const float xv = x[t];
      for (int u = 0; u < 32; ++u) z[u] += xv * Wt[(size_t)s * 1024 + t * 32 + u];
    }
    float e[32], ps = 0.f;
    for (int u = 0; u < 32; ++u) { e[u] = expf(tanhf(z[u])); ps += e[u]; }
    const float inv = 1.f / (ps + EPS_K);
    for (int u = 0; u < 32; ++u) O[u] += e[u] * inv * x[u];
  }
  for (int u = 0; u < 32; ++u) atomicAdd(out + b * 32 + u, O[u]);
}

extern "C" void kernel_launch(void* const* d_in, const int* in_sizes, int n_in,
                              void* d_out, int out_size, void* d_ws, size_t ws_size,
                              hipStream_t stream) {
  const float* inp  = (const float*)d_in[0];   // (512,32,2048) f32
  const float* msk  = (const float*)d_in[1];   // (512,32,2048) f32
  const float* Wt   = (const float*)d_in[2];   // (2048,32,32)  f32
  const float* bias = (const float*)d_in[3];   // (2048,32)     f32
  float* out = (float*)d_out;                  // (512,32)      f32

  const size_t part_sz = (size_t)64 * 16384 * sizeof(float);           // 4 MiB
  const size_t wbf_sz  = (size_t)2048 * 1024 * sizeof(unsigned short); // 4 MiB
  const size_t y_sz    = (size_t)512 * 32 * 2048 * sizeof(unsigned short); // 64 MiB

  if (ws_size >= part_sz + wbf_sz + y_sz) {
    float* part = (float*)d_ws;
    unsigned short* Wbf = (unsigned short*)((char*)d_ws + part_sz);
    unsigned short* Y   = (unsigned short*)((char*)d_ws + part_sz + wbf_sz);
    repack<<<dim3(1024), dim3(512), 0, stream>>>(inp, msk, Y);
    wbf_prep<<<dim3(2048), dim3(256), 0, stream>>>(Wt, Wbf);
    attn_comp<<<dim3(1024), dim3(256), 0, stream>>>(Y, Wbf, bias, part);
    reduce_part<<<dim3(64), dim3(256), 0, stream>>>(part, out);
  } else {
    (void)hipMemsetAsync(out, 0, (size_t)out_size * sizeof(float), stream);
    attn_naive<<<dim3(64), dim3(256), 0, stream>>>(inp, msk, Wt, bias, out);
  }
}

// Round 7
// 332.614 us; speedup vs baseline: 1.0456x; 1.0456x over previous
//
#include <hip/hip_runtime.h>

#define EPS_K 1e-7f

typedef __attribute__((ext_vector_type(8)))  short          frag8;  // 8 bf16
typedef __attribute__((ext_vector_type(16))) float          accf16; // MFMA C/D
typedef __attribute__((ext_vector_type(4)))  unsigned short us4;    // 8B read
typedef __attribute__((ext_vector_type(4)))  float          f32x4;

__device__ __forceinline__ unsigned f2bf(float f) {
  union { float f; unsigned u; } v; v.f = f;
  unsigned u = v.u;
  u += 0x7FFFu + ((u >> 16) & 1u);   // RNE
  return u >> 16;
}
__device__ __forceinline__ float bf2f(unsigned short s) {
  union { unsigned u; float f; } v; v.u = ((unsigned)s) << 16;
  return v.f;
}
__device__ __forceinline__ unsigned pk_bf16(float lo, float hi) {
  return f2bf(lo) | (f2bf(hi) << 16);
}
__device__ __forceinline__ float rcp_f(float x) {
  return __builtin_amdgcn_rcpf(x);   // validated rounds 3-6: absmax unchanged
}

// ---------------------------------------------------------------------------
// Pre-pass: W (2048,32,32) f32 [s][t][u] -> Wbf bf16 [s][u][t] (verified)
// ---------------------------------------------------------------------------
__global__ __launch_bounds__(256) void wbf_prep(
    const float* __restrict__ Wt, unsigned short* __restrict__ Wbf)
{
  __shared__ unsigned short tile[32 * 33];
  const int s   = blockIdx.x;
  const int tid = threadIdx.x;
  {
    const int t  = tid >> 3;
    const int uc = tid & 7;
    const float4 v = *(const float4*)(Wt + s * 1024 + t * 32 + 4 * uc);
    tile[t * 33 + 4 * uc + 0] = (unsigned short)f2bf(v.x);
    tile[t * 33 + 4 * uc + 1] = (unsigned short)f2bf(v.y);
    tile[t * 33 + 4 * uc + 2] = (unsigned short)f2bf(v.z);
    tile[t * 33 + 4 * uc + 3] = (unsigned short)f2bf(v.w);
  }
  __syncthreads();
  {
    const int u  = tid >> 3;
    const int tc = tid & 7;
    uint2 d;
    d.x = (unsigned)tile[(4 * tc + 0) * 33 + u] | ((unsigned)tile[(4 * tc + 1) * 33 + u] << 16);
    d.y = (unsigned)tile[(4 * tc + 2) * 33 + u] | ((unsigned)tile[(4 * tc + 3) * 33 + u] << 16);
    *(uint2*)(Wbf + s * 1024 + u * 32 + 4 * tc) = d;
  }
}

// ---------------------------------------------------------------------------
// Pass 1: repack x = inp*msk -> Y. Identical tiling / LDS layout / Y layout
// to round 6 (verified). ONLY the load phase changed: all 32 global loads
// (16 KB/wave) issued as inline-asm volatile (program-ordered, fire-and-
// forget -> compiler CANNOT sink them to point-of-use), consumed under
// counted s_waitcnt vmcnt(16) / vmcnt(0), each followed by sched_barrier(0)
// so no consumer is hoisted above the wait (rule #18). This pins >=16 KB
// in flight per wave by construction — the direct test of the "compiler
// serializes the load stream" theory of the 2.1 TB/s cap.
// __launch_bounds__(512,2): 256-VGPR budget, the 128 load VGPRs can't spill.
// ---------------------------------------------------------------------------
__global__ __launch_bounds__(512, 2) void repack(
    const float* __restrict__ inp, const float* __restrict__ msk,
    unsigned short* __restrict__ Y)
{
  __shared__ unsigned short sl[32768];          // 128 rows x 512 B = 64 KB
  const int tid  = threadIdx.x;
  const int lane = tid & 63;
  const int b7   = tid >> 6;                    // wave id = b' 0..7
  const int Q    = blockIdx.x & 63;             // b quarter
  const int w    = blockIdx.x >> 6;             // s-window 0..15
  const int l31  = lane & 31;                   // s-quad index
  const int l5   = lane >> 5;                   // c parity

  const size_t rb = ((size_t)(Q * 8 + b7) * 32 + 8 * l5) * 2048 + w * 128 + 4 * l31;
  const int slot = b7 ^ (l31 & 7);              // == b' ^ ((s>>2)&7) for all 4 k

  // ---- issue ALL 32 loads (16 KB/wave) before any consumer ----
  f32x4 vi[16], vm[16];                         // [c2*8+j], fully static idx
  #pragma unroll
  for (int c2 = 0; c2 < 2; ++c2) {
    #pragma unroll
    for (int j = 0; j < 8; ++j) {
      const float* ia = inp + rb + (size_t)(16 * c2 + j) * 2048; // t=16c2+8l5+j
      const float* ma = msk + rb + (size_t)(16 * c2 + j) * 2048;
      asm volatile("global_load_dwordx4 %0, %1, off"
                   : "=v"(vi[c2 * 8 + j]) : "v"(ia) : "memory");
      asm volatile("global_load_dwordx4 %0, %1, off"
                   : "=v"(vm[c2 * 8 + j]) : "v"(ma) : "memory");
    }
  }

  // ---- consume c2=0 once its 16 loads (the oldest) have landed ----
  asm volatile("s_waitcnt vmcnt(16)" ::: "memory");
  __builtin_amdgcn_sched_barrier(0);
  #pragma unroll
  for (int c2 = 0; c2 < 2; ++c2) {
    if (c2 == 1) {
      asm volatile("s_waitcnt vmcnt(0)" ::: "memory");
      __builtin_amdgcn_sched_barrier(0);
    }
    const int c   = 2 * c2 + l5;
    const int sid = c * 8 + slot;
    #pragma unroll
    for (int k = 0; k < 4; ++k) {
      const int s_loc = 4 * l31 + k;
      uint4 d;
      d.x = pk_bf16(vi[c2 * 8 + 0][k] * vm[c2 * 8 + 0][k],
                    vi[c2 * 8 + 1][k] * vm[c2 * 8 + 1][k]);
      d.y = pk_bf16(vi[c2 * 8 + 2][k] * vm[c2 * 8 + 2][k],
                    vi[c2 * 8 + 3][k] * vm[c2 * 8 + 3][k]);
      d.z = pk_bf16(vi[c2 * 8 + 4][k] * vm[c2 * 8 + 4][k],
                    vi[c2 * 8 + 5][k] * vm[c2 * 8 + 5][k]);
      d.w = pk_bf16(vi[c2 * 8 + 6][k] * vm[c2 * 8 + 6][k],
                    vi[c2 * 8 + 7][k] * vm[c2 * 8 + 7][k]);
      *(uint4*)(sl + s_loc * 256 + ((sid ^ (s_loc & 7)) * 8)) = d;
    }
  }
  __syncthreads();

  // ---- copy-out: 64-KB contiguous block (verified round 6) ----
  const size_t ybyte = ((size_t)Q * 2048 + (size_t)w * 128) * 512;
  #pragma unroll
  for (int i = 0; i < 8; ++i) {
    const int e  = i * 512 + tid;               // 16-B chunk 0..4095
    const int sv = e >> 5, ch = e & 31;
    const uint4 d = *(const uint4*)(sl + sv * 256 + ((ch ^ (sv & 7)) * 8));
    *(uint4*)((char*)Y + ybyte + (size_t)e * 16) = d;
  }
}

// ---------------------------------------------------------------------------
// Pass 2: compute (VERIFIED rounds 5/6, unchanged). 1024 blocks x 256 thr.
// MFMA C layout (HW-validated): col = lane&31 = b, row u = (r&3)+8*(r>>2)+4h.
// ---------------------------------------------------------------------------
__global__ __launch_bounds__(256, 4) void attn_comp(
    const unsigned short* __restrict__ Y,
    const unsigned short* __restrict__ Wbf,
    const float* __restrict__ bias,
    float* __restrict__ part)
{
  __shared__ float red[4096];                   // 16 KB epilogue scratch
  const int tid  = threadIdx.x;
  const int bg   = blockIdx.x & 15;
  const int sg   = blockIdx.x >> 4;             // 0..63
  const int lane = tid & 63;
  const int wv   = tid >> 6;
  const int n    = lane & 31;                   // b (B-frag col) / u (A-frag)
  const int h    = lane >> 5;

  const unsigned short* Yq = Y + ((size_t)(bg * 4 + (n >> 3)) * 2048) * 256;

  float O[16];
  #pragma unroll
  for (int r = 0; r < 16; ++r) O[r] = 0.f;

  #pragma unroll 2
  for (int it = 0; it < 8; ++it) {
    const int s = sg * 32 + wv * 8 + it;
    const unsigned short* slp = Yq + (size_t)s * 256;
    const int bt = (((n & 7) ^ ((s >> 2) & 7)) * 8);

    const frag8 b1 = *(const frag8*)(slp + h * 64 + bt);        // t=8h..8h+7
    const frag8 b2 = *(const frag8*)(slp + (h + 2) * 64 + bt);  // +16

    const unsigned short* wp = Wbf + (size_t)s * 1024 + n * 32 + 8 * h;
    const frag8 a1 = *(const frag8*)(wp);
    const frag8 a2 = *(const frag8*)(wp + 16);

    accf16 acc;
    #pragma unroll
    for (int g = 0; g < 4; ++g) {
      const f32x4 bb = *(const f32x4*)(bias + s * 32 + 8 * g + 4 * h);
      acc[4 * g + 0] = bb[0]; acc[4 * g + 1] = bb[1];
      acc[4 * g + 2] = bb[2]; acc[4 * g + 3] = bb[3];
    }
    acc = __builtin_amdgcn_mfma_f32_32x32x16_bf16(a1, b1, acc, 0, 0, 0);
    acc = __builtin_amdgcn_mfma_f32_32x32x16_bf16(a2, b2, acc, 0, 0, 0);

    // e = exp(tanh(z)); tanh(z) = 1 - 2/(exp(2z)+1)
    float ps = 0.f;
    #pragma unroll
    for (int r = 0; r < 16; ++r) {
      const float z  = acc[r];
      const float e2 = __expf(2.f * z);
      const float th = 1.f - 2.f * rcp_f(e2 + 1.f);
      acc[r] = __expf(th);
      ps    += acc[r];
    }
    const float tot = ps + __shfl_xor(ps, 32, 64);
    const float inv = rcp_f(tot + EPS_K);

    #pragma unroll
    for (int g = 0; g < 4; ++g) {
      const us4 xv = *(const us4*)(slp + g * 64 + bt + 4 * h);  // u=8g+4h+i
      #pragma unroll
      for (int i = 0; i < 4; ++i)
        O[4 * g + i] += acc[4 * g + i] * inv * bf2f(xv[i]);
    }
  }

  // ---- cross-wave reduction (verified) ----
  #pragma unroll
  for (int r = 0; r < 16; ++r) {
    const int u = (r & 3) + 8 * (r >> 2) + 4 * h;
    red[wv * 1024 + n * 32 + (u ^ n)] = O[r];
  }
  __syncthreads();

  const int q0 = tid * 4;
  f32x4 v;
  #pragma unroll
  for (int i = 0; i < 4; ++i) {
    const int q = q0 + i;
    const int b = q >> 5, u = q & 31;
    float sum = 0.f;
    #pragma unroll
    for (int w = 0; w < 4; ++w) sum += red[w * 1024 + b * 32 + (u ^ b)];
    v[i] = sum;
  }
  *(f32x4*)(part + (size_t)sg * 16384 + bg * 1024 + q0) = v;
}

// out[f] = sum over 64 s-groups of part[sg][f]
__global__ __launch_bounds__(256) void reduce_part(
    const float* __restrict__ part, float* __restrict__ out)
{
  const int f = blockIdx.x * 256 + threadIdx.x;
  float s = 0.f;
  #pragma unroll 8
  for (int sg = 0; sg < 64; ++sg) s += part[(size_t)sg * 16384 + f];
  out[f] = s;
}

// ---------------------------------------------------------------------------
// Safety fallback (ws too small): correct, slow, f32-precise.
// ---------------------------------------------------------------------------
__global__ __launch_bounds__(256) void attn_naive(
    const float* __restrict__ inp, const float* __restrict__ msk,
    const float* __restrict__ Wt, const float* __restrict__ bias,
    float* __restrict__ out)
{
  const int idx = blockIdx.x * 256 + threadIdx.x;  // 0..16383
  const int b = idx >> 5, sc = idx & 31;
  float O[32];
  #pragma unroll
  for (int u = 0; u < 32; ++u) O[u] = 0.f;
  for (int si = 0; si < 64; ++si) {
    const int s = sc * 64 + si;
    float x[32], z[32];
    for (int t = 0; t < 32; ++t) {
      x[t] = inp[((size_t)b * 32 + t) * 2048 + s] * msk[((size_t)b * 32 + t) * 2048 + s];
      z[t] = bias[s * 32 + t];
    }
    for (int t = 0; t < 32; ++t) {
      const float xv = x[t];
      for (int u = 0; u < 32; ++u) z[u] += xv * Wt[(size_t)s * 1024 + t * 32 + u];
    }
    float e[32], ps = 0.f;
    for (int u = 0; u < 32; ++u) { e[u] = expf(tanhf(z[u])); ps += e[u]; }
    const float inv = 1.f / (ps + EPS_K);
    for (int u = 0; u < 32; ++u) O[u] += e[u] * inv * x[u];
  }
  for (int u = 0; u < 32; ++u) atomicAdd(out + b * 32 + u, O[u]);
}

extern "C" void kernel_launch(void* const* d_in, const int* in_sizes, int n_in,
                              void* d_out, int out_size, void* d_ws, size_t ws_size,
                              hipStream_t stream) {
  const float* inp  = (const float*)d_in[0];   // (512,32,2048) f32
  const float* msk  = (const float*)d_in[1];   // (512,32,2048) f32
  const float* Wt   = (const float*)d_in[2];   // (2048,32,32)  f32
  const float* bias = (const float*)d_in[3];   // (2048,32)     f32
  float* out = (float*)d_out;                  // (512,32)      f32

  const size_t part_sz = (size_t)64 * 16384 * sizeof(float);           // 4 MiB
  const size_t wbf_sz  = (size_t)2048 * 1024 * sizeof(unsigned short); // 4 MiB
  const size_t y_sz    = (size_t)512 * 32 * 2048 * sizeof(unsigned short); // 64 MiB

  if (ws_size >= part_sz + wbf_sz + y_sz) {
    float* part = (float*)d_ws;
    unsigned short* Wbf = (unsigned short*)((char*)d_ws + part_sz);
    unsigned short* Y   = (unsigned short*)((char*)d_ws + part_sz + wbf_sz);
    repack<<<dim3(1024), dim3(512), 0, stream>>>(inp, msk, Y);
    wbf_prep<<<dim3(2048), dim3(256), 0, stream>>>(Wt, Wbf);
    attn_comp<<<dim3(1024), dim3(256), 0, stream>>>(Y, Wbf, bias, part);
    reduce_part<<<dim3(64), dim3(256), 0, stream>>>(part, out);
  } else {
    (void)hipMemsetAsync(out, 0, (size_t)out_size * sizeof(float), stream);
    attn_naive<<<dim3(64), dim3(256), 0, stream>>>(inp, msk, Wt, bias, out);
  }
}

// Round 8
// 306.147 us; speedup vs baseline: 1.1360x; 1.0865x over previous
//
#include <hip/hip_runtime.h>

#define EPS_K 1e-7f

typedef __attribute__((ext_vector_type(8)))  short          frag8;  // 8 bf16 (4 VGPRs)
typedef __attribute__((ext_vector_type(16))) float          accf16; // MFMA C/D
typedef __attribute__((ext_vector_type(4)))  unsigned short us4;    // 8B LDS read
typedef __attribute__((ext_vector_type(4)))  float          f32x4;

__device__ __forceinline__ unsigned f2bf(float f) {
  union { float f; unsigned u; } v; v.f = f;
  unsigned u = v.u;
  u += 0x7FFFu + ((u >> 16) & 1u);   // RNE
  return u >> 16;
}
__device__ __forceinline__ float bf2f(unsigned short s) {
  union { unsigned u; float f; } v; v.u = ((unsigned)s) << 16;
  return v.f;
}
__device__ __forceinline__ unsigned pk_bf16(float lo, float hi) {
  return f2bf(lo) | (f2bf(hi) << 16);
}
// streaming (no-allocate) load: the probe for the L3-thrash theory
__device__ __forceinline__ f32x4 ld_nt(const float* p) {
  return __builtin_nontemporal_load((const f32x4*)p);
}

// ---------------------------------------------------------------------------
// Pre-pass: W (2048,32,32) f32 [s][t][u]  ->  Wbf bf16 [s][u][t] (4 MB in ws)
// (verified, unchanged since round 0)
// ---------------------------------------------------------------------------
__global__ __launch_bounds__(256) void wbf_prep(
    const float* __restrict__ Wt, unsigned short* __restrict__ Wbf)
{
  __shared__ unsigned short tile[32 * 33];     // [t][u], pad 33
  const int s   = blockIdx.x;
  const int tid = threadIdx.x;
  {
    const int t  = tid >> 3;
    const int uc = tid & 7;                    // u-chunk of 4
    const float4 v = *(const float4*)(Wt + s * 1024 + t * 32 + 4 * uc);
    tile[t * 33 + 4 * uc + 0] = (unsigned short)f2bf(v.x);
    tile[t * 33 + 4 * uc + 1] = (unsigned short)f2bf(v.y);
    tile[t * 33 + 4 * uc + 2] = (unsigned short)f2bf(v.z);
    tile[t * 33 + 4 * uc + 3] = (unsigned short)f2bf(v.w);
  }
  __syncthreads();
  {
    const int u  = tid >> 3;
    const int tc = tid & 7;                    // t-chunk of 4
    uint2 d;
    d.x = (unsigned)tile[(4 * tc + 0) * 33 + u] | ((unsigned)tile[(4 * tc + 1) * 33 + u] << 16);
    d.y = (unsigned)tile[(4 * tc + 2) * 33 + u] | ((unsigned)tile[(4 * tc + 3) * 33 + u] << 16);
    *(uint2*)(Wbf + s * 1024 + u * 32 + 4 * tc) = d;  // lanes tc -> 64B contig
  }
}

// ---------------------------------------------------------------------------
// Main kernel: EXACT round-0 structure (best verified: 121.6 us, single pass,
// 268 MB read once). ONLY change: the 16 inp/msk staging loads are
// __builtin_nontemporal_load (no-allocate streaming) — probing whether the
// L3 allocate/evict thrash of a 268-MB stream vs 256-MB L3 is the 2.3 TB/s
// demand-rate cap seen in ALL eight structures so far.
//
// Per s: Z^T = A*B, A[m=u][k=t]=W[s][t][u], B[k=t][n=b]=x[b][t].
// C layout (32x32, HW-validated): col = lane&31 = b,
//   row = (r&3)+8*(r>>2)+4*(lane>>5) = u.
// x-tile LDS (bf16): per-b region of 64 16B-chunks; chunk L = (t>>3)*16 + s,
// swizzled L' = L ^ (b&7); element within chunk = t&7.
// ---------------------------------------------------------------------------
template <bool WBF, bool USE_WS>
__global__ __launch_bounds__(256, 5) void attn_fused(
    const float* __restrict__ inp,
    const float* __restrict__ msk,
    const float* __restrict__ Wt,
    const unsigned short* __restrict__ Wbf,
    const float* __restrict__ bias,
    float* __restrict__ part,
    float* __restrict__ out)
{
  __shared__ unsigned short x_us[32 * 512];    // 32 KB

  const int tid = threadIdx.x;
  const int st  = blockIdx.x >> 4;             // s-tile 0..127
  const int bg  = blockIdx.x & 15;             // b-group 0..15
  const int s0  = st * 16;

  // ---- stage x = inp*msk (thread owns b, 8 t, 4 s -> whole 16B chunks) ----
  #pragma unroll
  for (int iter = 0; iter < 2; ++iter) {
    const int idx = iter * 256 + tid;
    const int sc  = idx & 3;                   // s-quad
    const int tb  = (idx >> 2) & 3;            // t-block of 8
    const int b   = idx >> 4;                  // 0..31
    const float* ip = inp + ((size_t)(bg * 32 + b) * 32 + 8 * tb) * 2048 + s0 + 4 * sc;
    const float* mp = msk + ((size_t)(bg * 32 + b) * 32 + 8 * tb) * 2048 + s0 + 4 * sc;
    unsigned c32[4][4];                        // [w][dword j2]
    #pragma unroll
    for (int j2 = 0; j2 < 4; ++j2) {
      const f32x4 vi0 = ld_nt(ip + (2 * j2)     * 2048);
      const f32x4 vm0 = ld_nt(mp + (2 * j2)     * 2048);
      const f32x4 vi1 = ld_nt(ip + (2 * j2 + 1) * 2048);
      const f32x4 vm1 = ld_nt(mp + (2 * j2 + 1) * 2048);
      c32[0][j2] = pk_bf16(vi0[0] * vm0[0], vi1[0] * vm1[0]);
      c32[1][j2] = pk_bf16(vi0[1] * vm0[1], vi1[1] * vm1[1]);
      c32[2][j2] = pk_bf16(vi0[2] * vm0[2], vi1[2] * vm1[2]);
      c32[3][j2] = pk_bf16(vi0[3] * vm0[3], vi1[3] * vm1[3]);
    }
    #pragma unroll
    for (int w = 0; w < 4; ++w) {
      const int L = tb * 16 + 4 * sc + w;
      unsigned* dst = (unsigned*)(x_us + b * 512 + ((L ^ (b & 7)) * 8));
      *(uint4*)dst = make_uint4(c32[w][0], c32[w][1], c32[w][2], c32[w][3]);
    }
  }
  __syncthreads();

  const int lane = tid & 63;
  const int wv   = tid >> 6;                   // wave 0..3 -> s_local = wv*4+si
  const int n    = lane & 31;                  // b (B-frag n, C col) / u (A-frag m)
  const int h    = lane >> 5;                  // half-wave -> k-block / row group
  const int nx   = n & 7;

  float O[16];
  #pragma unroll
  for (int r = 0; r < 16; ++r) O[r] = 0.f;

  #pragma unroll
  for (int si = 0; si < 4; ++si) {
    const int sl = wv * 4 + si;
    const int s  = s0 + sl;

    // A-frag
    frag8 a1, a2;
    if (WBF) {
      const unsigned short* wp = Wbf + s * 1024 + n * 32 + 8 * h;
      a1 = *(const frag8*)(wp);
      a2 = *(const frag8*)(wp + 16);
    } else {
      const float* Wp = Wt + s * 1024;
      #pragma unroll
      for (int j = 0; j < 8; ++j) {
        const int t1 = 8 * h + j;
        a1[j] = (short)f2bf(Wp[t1 * 32 + n]);
        a2[j] = (short)f2bf(Wp[(t1 + 16) * 32 + n]);
      }
    }

    // B-frag: chunks L = h*16+sl (t=8h..8h+7) and (h+2)*16+sl (t=+16)
    const frag8 b1 = *(const frag8*)(x_us + n * 512 + (((h      * 16 + sl) ^ nx) * 8));
    const frag8 b2 = *(const frag8*)(x_us + n * 512 + ((((h + 2) * 16 + sl) ^ nx) * 8));

    // bias -> accumulator init (4 broadcast dwordx4)
    accf16 acc;
    #pragma unroll
    for (int g = 0; g < 4; ++g) {
      const float4 bb = *(const float4*)(bias + s * 32 + 8 * g + 4 * h);
      acc[4 * g + 0] = bb.x; acc[4 * g + 1] = bb.y;
      acc[4 * g + 2] = bb.z; acc[4 * g + 3] = bb.w;
    }
    acc = __builtin_amdgcn_mfma_f32_32x32x16_bf16(a1, b1, acc, 0, 0, 0);
    acc = __builtin_amdgcn_mfma_f32_32x32x16_bf16(a2, b2, acc, 0, 0, 0);

    // e = exp(tanh(z)); tanh(z) = 1 - 2/(exp(2z)+1)
    float e[16];
    float ps = 0.f;
    #pragma unroll
    for (int r = 0; r < 16; ++r) {
      const float z  = acc[r];
      const float e2 = __expf(2.f * z);
      const float th = 1.f - 2.f / (e2 + 1.f);
      e[r] = __expf(th);
      ps  += e[r];
    }
    const float tot = ps + __shfl_xor(ps, 32, 64);
    const float inv = 1.f / (tot + EPS_K);

    // O += att * x ; x re-read as 4 x ds_read_b64 (u = 8g+4h+i -> r = 4g+i)
    #pragma unroll
    for (int g = 0; g < 4; ++g) {
      const us4 xv = *(const us4*)(x_us + n * 512 + (((g * 16 + sl) ^ nx) * 8) + 4 * h);
      #pragma unroll
      for (int i = 0; i < 4; ++i)
        O[4 * g + i] += e[4 * g + i] * inv * bf2f(xv[i]);
    }
  }

  // ---- cross-wave reduction in LDS (no atomics) ----
  __syncthreads();
  float* red = (float*)x_us;
  #pragma unroll
  for (int r = 0; r < 16; ++r) {
    const int u = (r & 3) + 8 * (r >> 2) + 4 * h;
    red[wv * 1024 + n * 32 + (u ^ n)] = O[r];
  }
  __syncthreads();

  const int q0 = tid * 4;
  float4 v;
  float* vp = (float*)&v;
  #pragma unroll
  for (int i = 0; i < 4; ++i) {
    const int q = q0 + i;
    const int b = q >> 5, u = q & 31;
    float sum = 0.f;
    #pragma unroll
    for (int w = 0; w < 4; ++w) sum += red[w * 1024 + b * 32 + (u ^ b)];
    vp[i] = sum;
  }
  if (USE_WS) {
    *(float4*)(part + (size_t)st * 16384 + bg * 1024 + q0) = v;
  } else {
    float* op = out + bg * 1024 + q0;
    #pragma unroll
    for (int i = 0; i < 4; ++i) atomicAdd(op + i, vp[i]);
  }
}

// out[f] = sum over 128 s-tiles of part[st][f]
__global__ __launch_bounds__(256) void reduce_part(
    const float* __restrict__ part, float* __restrict__ out)
{
  const int f = blockIdx.x * 256 + threadIdx.x;
  float s = 0.f;
  #pragma unroll 8
  for (int st = 0; st < 128; ++st) s += part[(size_t)st * 16384 + f];
  out[f] = s;
}

extern "C" void kernel_launch(void* const* d_in, const int* in_sizes, int n_in,
                              void* d_out, int out_size, void* d_ws, size_t ws_size,
                              hipStream_t stream) {
  const float* inp  = (const float*)d_in[0];   // (512,32,2048) f32
  const float* msk  = (const float*)d_in[1];   // (512,32,2048) f32
  const float* Wt   = (const float*)d_in[2];   // (2048,32,32)  f32
  const float* bias = (const float*)d_in[3];   // (2048,32)     f32
  float* out = (float*)d_out;                  // (512,32)      f32

  const size_t part_sz = (size_t)128 * 16384 * sizeof(float);          // 8 MB
  const size_t wbf_sz  = (size_t)2048 * 1024 * sizeof(unsigned short); // 4 MB

  if (ws_size >= part_sz + wbf_sz) {
    float* part = (float*)d_ws;
    unsigned short* Wbf = (unsigned short*)((char*)d_ws + part_sz);
    wbf_prep<<<dim3(2048), dim3(256), 0, stream>>>(Wt, Wbf);
    attn_fused<true, true><<<dim3(2048), dim3(256), 0, stream>>>(
        inp, msk, Wt, Wbf, bias, part, out);
    reduce_part<<<dim3(64), dim3(256), 0, stream>>>(part, out);
  } else if (ws_size >= part_sz) {
    float* part = (float*)d_ws;
    attn_fused<false, true><<<dim3(2048), dim3(256), 0, stream>>>(
        inp, msk, Wt, nullptr, bias, part, out);
    reduce_part<<<dim3(64), dim3(256), 0, stream>>>(part, out);
  } else {
    (void)hipMemsetAsync(out, 0, (size_t)out_size * sizeof(float), stream);
    attn_fused<false, false><<<dim3(2048), dim3(256), 0, stream>>>(
        inp, msk, Wt, nullptr, bias, nullptr, out);
  }
}

// Round 9
// 302.034 us; speedup vs baseline: 1.1514x; 1.0136x over previous
//
#include <hip/hip_runtime.h>

#define EPS_K 1e-7f

typedef __attribute__((ext_vector_type(8)))  short          frag8;  // 8 bf16 (4 VGPRs)
typedef __attribute__((ext_vector_type(16))) float          accf16; // MFMA C/D
typedef __attribute__((ext_vector_type(4)))  unsigned short us4;    // 8B LDS read
typedef __attribute__((ext_vector_type(4)))  float          f32x4;

__device__ __forceinline__ unsigned f2bf(float f) {
  union { float f; unsigned u; } v; v.f = f;
  unsigned u = v.u;
  u += 0x7FFFu + ((u >> 16) & 1u);   // RNE
  return u >> 16;
}
__device__ __forceinline__ float bf2f(unsigned short s) {
  union { unsigned u; float f; } v; v.u = ((unsigned)s) << 16;
  return v.f;
}
__device__ __forceinline__ unsigned pk_bf16(float lo, float hi) {
  return f2bf(lo) | (f2bf(hi) << 16);
}

// ---------------------------------------------------------------------------
// Pre-pass: W (2048,32,32) f32 [s][t][u]  ->  Wbf bf16 [s][u][t] (4 MB in ws)
// (verified, unchanged since round 0)
// ---------------------------------------------------------------------------
__global__ __launch_bounds__(256) void wbf_prep(
    const float* __restrict__ Wt, unsigned short* __restrict__ Wbf)
{
  __shared__ unsigned short tile[32 * 33];     // [t][u], pad 33
  const int s   = blockIdx.x;
  const int tid = threadIdx.x;
  {
    const int t  = tid >> 3;
    const int uc = tid & 7;                    // u-chunk of 4
    const float4 v = *(const float4*)(Wt + s * 1024 + t * 32 + 4 * uc);
    tile[t * 33 + 4 * uc + 0] = (unsigned short)f2bf(v.x);
    tile[t * 33 + 4 * uc + 1] = (unsigned short)f2bf(v.y);
    tile[t * 33 + 4 * uc + 2] = (unsigned short)f2bf(v.z);
    tile[t * 33 + 4 * uc + 3] = (unsigned short)f2bf(v.w);
  }
  __syncthreads();
  {
    const int u  = tid >> 3;
    const int tc = tid & 7;                    // t-chunk of 4
    uint2 d;
    d.x = (unsigned)tile[(4 * tc + 0) * 33 + u] | ((unsigned)tile[(4 * tc + 1) * 33 + u] << 16);
    d.y = (unsigned)tile[(4 * tc + 2) * 33 + u] | ((unsigned)tile[(4 * tc + 3) * 33 + u] << 16);
    *(uint2*)(Wbf + s * 1024 + u * 32 + 4 * tc) = d;  // lanes tc -> 64B contig
  }
}

// ---------------------------------------------------------------------------
// Main kernel: round-8 structure (nt loads, 88.7 us verified). ONE change:
// the 32 staging loads are issued as inline-asm `global_load_dwordx4 .. nt`
// — program-ordered, fire-and-forget, ALL issued before any consumer —
// consumed under counted vmcnt(16)/vmcnt(0) + sched_barrier(0) (rule #18).
// This combines the two individually-proven mechanisms:
//   nt (R8, +27%: kills L3 allocate thrash) x pinned depth (R7 mechanics:
//   compiler provably sinks loads to consumers at VGPR=48 -> ~3 loads/wave
//   in flight -> 2.4 TB/s by Little's law). 512 B/thread pinned in flight.
// __launch_bounds__(256,2): ~160-VGPR live set cannot spill (R3 lesson).
//
// Per s: Z^T = A*B, A[m=u][k=t]=W[s][t][u], B[k=t][n=b]=x[b][t].
// C layout (32x32, HW-validated): col = lane&31 = b,
//   row = (r&3)+8*(r>>2)+4*(lane>>5) = u.
// x-tile LDS (bf16): per-b region of 64 16B-chunks; chunk L = (t>>3)*16 + s,
// swizzled L' = L ^ (b&7); element within chunk = t&7.
// ---------------------------------------------------------------------------
template <bool WBF, bool USE_WS>
__global__ __launch_bounds__(256, 2) void attn_fused(
    const float* __restrict__ inp,
    const float* __restrict__ msk,
    const float* __restrict__ Wt,
    const unsigned short* __restrict__ Wbf,
    const float* __restrict__ bias,
    float* __restrict__ part,
    float* __restrict__ out)
{
  __shared__ unsigned short x_us[32 * 512];    // 32 KB

  const int tid = threadIdx.x;
  const int st  = blockIdx.x >> 4;             // s-tile 0..127
  const int bg  = blockIdx.x & 15;             // b-group 0..15
  const int s0  = st * 16;

  // ---- stage x = inp*msk: issue ALL 32 nt loads, then consume counted ----
  f32x4 vi[2][8], vm[2][8];                    // [iter][t-row] : 128 VGPR
  {
    const float* ipb[2];
    const float* mpb[2];
    #pragma unroll
    for (int it = 0; it < 2; ++it) {
      const int idx = it * 256 + tid;
      const int sc  = idx & 3;                 // s-quad
      const int tb  = (idx >> 2) & 3;          // t-block of 8
      const int b   = idx >> 4;                // 0..31
      ipb[it] = inp + ((size_t)(bg * 32 + b) * 32 + 8 * tb) * 2048 + s0 + 4 * sc;
      mpb[it] = msk + ((size_t)(bg * 32 + b) * 32 + 8 * tb) * 2048 + s0 + 4 * sc;
    }
    #pragma unroll
    for (int it = 0; it < 2; ++it) {
      #pragma unroll
      for (int r = 0; r < 8; ++r) {            // t row within 8-t block
        asm volatile("global_load_dwordx4 %0, %1, off nt"
                     : "=v"(vi[it][r]) : "v"(ipb[it] + r * 2048) : "memory");
        asm volatile("global_load_dwordx4 %0, %1, off nt"
                     : "=v"(vm[it][r]) : "v"(mpb[it] + r * 2048) : "memory");
      }
    }
    // consume iter 0 when its 16 (oldest) loads have landed; iter-1's 16
    // stay in flight underneath the pack+LDS-write.
    asm volatile("s_waitcnt vmcnt(16)" ::: "memory");
    __builtin_amdgcn_sched_barrier(0);
    #pragma unroll
    for (int it = 0; it < 2; ++it) {
      if (it == 1) {
        asm volatile("s_waitcnt vmcnt(0)" ::: "memory");
        __builtin_amdgcn_sched_barrier(0);
      }
      const int idx = it * 256 + tid;
      const int sc  = idx & 3;
      const int tb  = (idx >> 2) & 3;
      const int b   = idx >> 4;
      unsigned c32[4][4];                      // [w][dword j2]
      #pragma unroll
      for (int j2 = 0; j2 < 4; ++j2) {
        #pragma unroll
        for (int w = 0; w < 4; ++w)
          c32[w][j2] = pk_bf16(vi[it][2 * j2][w] * vm[it][2 * j2][w],
                               vi[it][2 * j2 + 1][w] * vm[it][2 * j2 + 1][w]);
      }
      #pragma unroll
      for (int w = 0; w < 4; ++w) {
        const int L = tb * 16 + 4 * sc + w;
        unsigned* dst = (unsigned*)(x_us + b * 512 + ((L ^ (b & 7)) * 8));
        *(uint4*)dst = make_uint4(c32[w][0], c32[w][1], c32[w][2], c32[w][3]);
      }
    }
  }
  __syncthreads();

  const int lane = tid & 63;
  const int wv   = tid >> 6;                   // wave 0..3 -> s_local = wv*4+si
  const int n    = lane & 31;                  // b (B-frag n, C col) / u (A-frag m)
  const int h    = lane >> 5;                  // half-wave -> k-block / row group
  const int nx   = n & 7;

  float O[16];
  #pragma unroll
  for (int r = 0; r < 16; ++r) O[r] = 0.f;

  #pragma unroll
  for (int si = 0; si < 4; ++si) {
    const int sl = wv * 4 + si;
    const int s  = s0 + sl;

    // A-frag
    frag8 a1, a2;
    if (WBF) {
      const unsigned short* wp = Wbf + s * 1024 + n * 32 + 8 * h;
      a1 = *(const frag8*)(wp);
      a2 = *(const frag8*)(wp + 16);
    } else {
      const float* Wp = Wt + s * 1024;
      #pragma unroll
      for (int j = 0; j < 8; ++j) {
        const int t1 = 8 * h + j;
        a1[j] = (short)f2bf(Wp[t1 * 32 + n]);
        a2[j] = (short)f2bf(Wp[(t1 + 16) * 32 + n]);
      }
    }

    // B-frag: chunks L = h*16+sl (t=8h..8h+7) and (h+2)*16+sl (t=+16)
    const frag8 b1 = *(const frag8*)(x_us + n * 512 + (((h      * 16 + sl) ^ nx) * 8));
    const frag8 b2 = *(const frag8*)(x_us + n * 512 + ((((h + 2) * 16 + sl) ^ nx) * 8));

    // bias -> accumulator init (4 broadcast dwordx4)
    accf16 acc;
    #pragma unroll
    for (int g = 0; g < 4; ++g) {
      const float4 bb = *(const float4*)(bias + s * 32 + 8 * g + 4 * h);
      acc[4 * g + 0] = bb.x; acc[4 * g + 1] = bb.y;
      acc[4 * g + 2] = bb.z; acc[4 * g + 3] = bb.w;
    }
    acc = __builtin_amdgcn_mfma_f32_32x32x16_bf16(a1, b1, acc, 0, 0, 0);
    acc = __builtin_amdgcn_mfma_f32_32x32x16_bf16(a2, b2, acc, 0, 0, 0);

    // e = exp(tanh(z)); tanh(z) = 1 - 2/(exp(2z)+1)
    float e[16];
    float ps = 0.f;
    #pragma unroll
    for (int r = 0; r < 16; ++r) {
      const float z  = acc[r];
      const float e2 = __expf(2.f * z);
      const float th = 1.f - 2.f / (e2 + 1.f);
      e[r] = __expf(th);
      ps  += e[r];
    }
    const float tot = ps + __shfl_xor(ps, 32, 64);
    const float inv = 1.f / (tot + EPS_K);

    // O += att * x ; x re-read as 4 x ds_read_b64 (u = 8g+4h+i -> r = 4g+i)
    #pragma unroll
    for (int g = 0; g < 4; ++g) {
      const us4 xv = *(const us4*)(x_us + n * 512 + (((g * 16 + sl) ^ nx) * 8) + 4 * h);
      #pragma unroll
      for (int i = 0; i < 4; ++i)
        O[4 * g + i] += e[4 * g + i] * inv * bf2f(xv[i]);
    }
  }

  // ---- cross-wave reduction in LDS (no atomics) ----
  __syncthreads();
  float* red = (float*)x_us;
  #pragma unroll
  for (int r = 0; r < 16; ++r) {
    const int u = (r & 3) + 8 * (r >> 2) + 4 * h;
    red[wv * 1024 + n * 32 + (u ^ n)] = O[r];
  }
  __syncthreads();

  const int q0 = tid * 4;
  float4 v;
  float* vp = (float*)&v;
  #pragma unroll
  for (int i = 0; i < 4; ++i) {
    const int q = q0 + i;
    const int b = q >> 5, u = q & 31;
    float sum = 0.f;
    #pragma unroll
    for (int w = 0; w < 4; ++w) sum += red[w * 1024 + b * 32 + (u ^ b)];
    vp[i] = sum;
  }
  if (USE_WS) {
    *(float4*)(part + (size_t)st * 16384 + bg * 1024 + q0) = v;
  } else {
    float* op = out + bg * 1024 + q0;
    #pragma unroll
    for (int i = 0; i < 4; ++i) atomicAdd(op + i, vp[i]);
  }
}

// out[f] = sum over 128 s-tiles of part[st][f]
__global__ __launch_bounds__(256) void reduce_part(
    const float* __restrict__ part, float* __restrict__ out)
{
  const int f = blockIdx.x * 256 + threadIdx.x;
  float s = 0.f;
  #pragma unroll 8
  for (int st = 0; st < 128; ++st) s += part[(size_t)st * 16384 + f];
  out[f] = s;
}

extern "C" void kernel_launch(void* const* d_in, const int* in_sizes, int n_in,
                              void* d_out, int out_size, void* d_ws, size_t ws_size,
                              hipStream_t stream) {
  const float* inp  = (const float*)d_in[0];   // (512,32,2048) f32
  const float* msk  = (const float*)d_in[1];   // (512,32,2048) f32
  const float* Wt   = (const float*)d_in[2];   // (2048,32,32)  f32
  const float* bias = (const float*)d_in[3];   // (2048,32)     f32
  float* out = (float*)d_out;                  // (512,32)      f32

  const size_t part_sz = (size_t)128 * 16384 * sizeof(float);          // 8 MB
  const size_t wbf_sz  = (size_t)2048 * 1024 * sizeof(unsigned short); // 4 MB

  if (ws_size >= part_sz + wbf_sz) {
    float* part = (float*)d_ws;
    unsigned short* Wbf = (unsigned short*)((char*)d_ws + part_sz);
    wbf_prep<<<dim3(2048), dim3(256), 0, stream>>>(Wt, Wbf);
    attn_fused<true, true><<<dim3(2048), dim3(256), 0, stream>>>(
        inp, msk, Wt, Wbf, bias, part, out);
    reduce_part<<<dim3(64), dim3(256), 0, stream>>>(part, out);
  } else if (ws_size >= part_sz) {
    float* part = (float*)d_ws;
    attn_fused<false, true><<<dim3(2048), dim3(256), 0, stream>>>(
        inp, msk, Wt, nullptr, bias, part, out);
    reduce_part<<<dim3(64), dim3(256), 0, stream>>>(part, out);
  } else {
    (void)hipMemsetAsync(out, 0, (size_t)out_size * sizeof(float), stream);
    attn_fused<false, false><<<dim3(2048), dim3(256), 0, stream>>>(
        inp, msk, Wt, nullptr, bias, nullptr, out);
  }
}

// Round 10
// 286.458 us; speedup vs baseline: 1.2140x; 1.0544x over previous
//
#include <hip/hip_runtime.h>

#define EPS_K 1e-7f

typedef __attribute__((ext_vector_type(8)))  short          frag8;  // 8 bf16 (4 VGPRs)
typedef __attribute__((ext_vector_type(16))) float          accf16; // MFMA C/D
typedef __attribute__((ext_vector_type(4)))  unsigned short us4;    // 8B LDS read
typedef __attribute__((ext_vector_type(4)))  float          f32x4;

__device__ __forceinline__ unsigned f2bf(float f) {
  union { float f; unsigned u; } v; v.f = f;
  unsigned u = v.u;
  u += 0x7FFFu + ((u >> 16) & 1u);   // RNE
  return u >> 16;
}
__device__ __forceinline__ float bf2f(unsigned short s) {
  union { unsigned u; float f; } v; v.u = ((unsigned)s) << 16;
  return v.f;
}
__device__ __forceinline__ unsigned pk_bf16(float lo, float hi) {
  return f2bf(lo) | (f2bf(hi) << 16);
}
// streaming (no-allocate) load — R8-proven (+27%); compiler-scheduled (R9:
// manual pinning regresses).
__device__ __forceinline__ f32x4 ld_nt(const float* p) {
  return __builtin_nontemporal_load((const f32x4*)p);
}

// ---------------------------------------------------------------------------
// Pre-pass: W (2048,32,32) f32 [s][t][u]  ->  Wbf bf16 [s][u][t] (4 MB in ws)
// (verified, unchanged since round 0)
// ---------------------------------------------------------------------------
__global__ __launch_bounds__(256) void wbf_prep(
    const float* __restrict__ Wt, unsigned short* __restrict__ Wbf)
{
  __shared__ unsigned short tile[32 * 33];     // [t][u], pad 33
  const int s   = blockIdx.x;
  const int tid = threadIdx.x;
  {
    const int t  = tid >> 3;
    const int uc = tid & 7;                    // u-chunk of 4
    const float4 v = *(const float4*)(Wt + s * 1024 + t * 32 + 4 * uc);
    tile[t * 33 + 4 * uc + 0] = (unsigned short)f2bf(v.x);
    tile[t * 33 + 4 * uc + 1] = (unsigned short)f2bf(v.y);
    tile[t * 33 + 4 * uc + 2] = (unsigned short)f2bf(v.z);
    tile[t * 33 + 4 * uc + 3] = (unsigned short)f2bf(v.w);
  }
  __syncthreads();
  {
    const int u  = tid >> 3;
    const int tc = tid & 7;                    // t-chunk of 4
    uint2 d;
    d.x = (unsigned)tile[(4 * tc + 0) * 33 + u] | ((unsigned)tile[(4 * tc + 1) * 33 + u] << 16);
    d.y = (unsigned)tile[(4 * tc + 2) * 33 + u] | ((unsigned)tile[(4 * tc + 3) * 33 + u] << 16);
    *(uint2*)(Wbf + s * 1024 + u * 32 + 4 * tc) = d;  // lanes tc -> 64B contig
  }
}

// ---------------------------------------------------------------------------
// Main kernel: R8 structure with the s-tile widened 16 -> 32 so each staging
// read is a 128-B contiguous chunk (8 lanes x 16 B per (b,t) row) instead of
// 64-B — the DRAM-granularity probe, the last untested mechanism (nt held
// constant from R8's +27%).
//
// Tile: 32 s x 32 b. Grid 1024 = 64 st x 16 bg, 512 thr (8 waves).
// LDS x-tile 64 KB: per-b 1024 ushorts = 128 chunks of 8 bf16;
//   chunk L = (t>>3)*32 + s_loc, swizzled L ^ (b&7)  (R0-verified identity,
//   L-range doubled; L&7 unchanged by the c-term (32 === 0 mod 8) so the
//   bank math is exactly R0/R8's: B-frag reads 2-way/broadcast = free).
// Compute: wave wv owns sl = wv*4+si (0..31); fragment/C-layout math
// byte-identical to verified R0/R8. Epilogue: 8-wave LDS reduction (32 KB,
// reuses x_us), part[st][f] + reduce pass.
// __launch_bounds__(512,2): VGPR cap 256, no forced spill (R1/R9 lesson).
// ---------------------------------------------------------------------------
template <bool WBF, bool USE_WS>
__global__ __launch_bounds__(512, 2) void attn_fused(
    const float* __restrict__ inp,
    const float* __restrict__ msk,
    const float* __restrict__ Wt,
    const unsigned short* __restrict__ Wbf,
    const float* __restrict__ bias,
    float* __restrict__ part,
    float* __restrict__ out)
{
  __shared__ unsigned short x_us[32 * 1024];   // 64 KB

  const int tid = threadIdx.x;
  const int st  = blockIdx.x >> 4;             // s-tile 0..63 (32 s each)
  const int bg  = blockIdx.x & 15;             // b-group 0..15
  const int s0  = st * 32;

  // ---- stage x = inp*msk (thread: b, 8 t, 4 s; 8-lane groups = 128 B) ----
  #pragma unroll
  for (int it = 0; it < 2; ++it) {
    const int idx = it * 512 + tid;
    const int sc  = idx & 7;                   // s-quad 0..7 -> 32 s
    const int tb  = (idx >> 3) & 3;            // t-block of 8
    const int b   = idx >> 5;                  // 0..31
    const float* ip = inp + ((size_t)(bg * 32 + b) * 32 + 8 * tb) * 2048 + s0 + 4 * sc;
    const float* mp = msk + ((size_t)(bg * 32 + b) * 32 + 8 * tb) * 2048 + s0 + 4 * sc;
    unsigned c32[4][4];                        // [w][dword j2]
    #pragma unroll
    for (int j2 = 0; j2 < 4; ++j2) {
      const f32x4 vi0 = ld_nt(ip + (2 * j2)     * 2048);
      const f32x4 vm0 = ld_nt(mp + (2 * j2)     * 2048);
      const f32x4 vi1 = ld_nt(ip + (2 * j2 + 1) * 2048);
      const f32x4 vm1 = ld_nt(mp + (2 * j2 + 1) * 2048);
      c32[0][j2] = pk_bf16(vi0[0] * vm0[0], vi1[0] * vm1[0]);
      c32[1][j2] = pk_bf16(vi0[1] * vm0[1], vi1[1] * vm1[1]);
      c32[2][j2] = pk_bf16(vi0[2] * vm0[2], vi1[2] * vm1[2]);
      c32[3][j2] = pk_bf16(vi0[3] * vm0[3], vi1[3] * vm1[3]);
    }
    #pragma unroll
    for (int w = 0; w < 4; ++w) {
      const int L = tb * 32 + 4 * sc + w;      // 0..127
      unsigned* dst = (unsigned*)(x_us + b * 1024 + ((L ^ (b & 7)) * 8));
      *(uint4*)dst = make_uint4(c32[w][0], c32[w][1], c32[w][2], c32[w][3]);
    }
  }
  __syncthreads();

  const int lane = tid & 63;
  const int wv   = tid >> 6;                   // wave 0..7 -> sl = wv*4+si
  const int n    = lane & 31;                  // b (B-frag n, C col) / u (A-frag m)
  const int h    = lane >> 5;                  // half-wave -> k-block / row group
  const int nx   = n & 7;

  float O[16];
  #pragma unroll
  for (int r = 0; r < 16; ++r) O[r] = 0.f;

  #pragma unroll
  for (int si = 0; si < 4; ++si) {
    const int sl = wv * 4 + si;                // 0..31
    const int s  = s0 + sl;

    // A-frag
    frag8 a1, a2;
    if (WBF) {
      const unsigned short* wp = Wbf + s * 1024 + n * 32 + 8 * h;
      a1 = *(const frag8*)(wp);
      a2 = *(const frag8*)(wp + 16);
    } else {
      const float* Wp = Wt + s * 1024;
      #pragma unroll
      for (int j = 0; j < 8; ++j) {
        const int t1 = 8 * h + j;
        a1[j] = (short)f2bf(Wp[t1 * 32 + n]);
        a2[j] = (short)f2bf(Wp[(t1 + 16) * 32 + n]);
      }
    }

    // B-frag: chunks L = h*32+sl (t=8h..8h+7) and (h+2)*32+sl (t=+16)
    const frag8 b1 = *(const frag8*)(x_us + n * 1024 + (((h      * 32 + sl) ^ nx) * 8));
    const frag8 b2 = *(const frag8*)(x_us + n * 1024 + ((((h + 2) * 32 + sl) ^ nx) * 8));

    // bias -> accumulator init (4 broadcast dwordx4)
    accf16 acc;
    #pragma unroll
    for (int g = 0; g < 4; ++g) {
      const float4 bb = *(const float4*)(bias + s * 32 + 8 * g + 4 * h);
      acc[4 * g + 0] = bb.x; acc[4 * g + 1] = bb.y;
      acc[4 * g + 2] = bb.z; acc[4 * g + 3] = bb.w;
    }
    acc = __builtin_amdgcn_mfma_f32_32x32x16_bf16(a1, b1, acc, 0, 0, 0);
    acc = __builtin_amdgcn_mfma_f32_32x32x16_bf16(a2, b2, acc, 0, 0, 0);

    // e = exp(tanh(z)); tanh(z) = 1 - 2/(exp(2z)+1)  (math identical to R8)
    float e[16];
    float ps = 0.f;
    #pragma unroll
    for (int r = 0; r < 16; ++r) {
      const float z  = acc[r];
      const float e2 = __expf(2.f * z);
      const float th = 1.f - 2.f / (e2 + 1.f);
      e[r] = __expf(th);
      ps  += e[r];
    }
    const float tot = ps + __shfl_xor(ps, 32, 64);
    const float inv = 1.f / (tot + EPS_K);

    // O += att * x ; x re-read as 4 x ds_read_b64 (u = 8g+4h+i -> r = 4g+i)
    #pragma unroll
    for (int g = 0; g < 4; ++g) {
      const us4 xv = *(const us4*)(x_us + n * 1024 + (((g * 32 + sl) ^ nx) * 8) + 4 * h);
      #pragma unroll
      for (int i = 0; i < 4; ++i)
        O[4 * g + i] += e[4 * g + i] * inv * bf2f(xv[i]);
    }
  }

  // ---- cross-wave reduction in LDS (8 waves x 1024 f32 = 32 KB, reuse) ----
  __syncthreads();
  float* red = (float*)x_us;
  #pragma unroll
  for (int r = 0; r < 16; ++r) {
    const int u = (r & 3) + 8 * (r >> 2) + 4 * h;
    red[wv * 1024 + n * 32 + (u ^ n)] = O[r];
  }
  __syncthreads();

  const int q0 = tid * 2;                      // 512 threads x 2 outputs
  float2 v;
  #pragma unroll
  for (int i = 0; i < 2; ++i) {
    const int q = q0 + i;
    const int b = q >> 5, u = q & 31;
    float sum = 0.f;
    #pragma unroll
    for (int w = 0; w < 8; ++w) sum += red[w * 1024 + b * 32 + (u ^ b)];
    (&v.x)[i] = sum;
  }
  if (USE_WS) {
    *(float2*)(part + (size_t)st * 16384 + bg * 1024 + q0) = v;
  } else {
    float* op = out + bg * 1024 + q0;
    atomicAdd(op + 0, v.x);
    atomicAdd(op + 1, v.y);
  }
}

// out[f] = sum over 64 s-tiles of part[st][f]
__global__ __launch_bounds__(256) void reduce_part(
    const float* __restrict__ part, float* __restrict__ out)
{
  const int f = blockIdx.x * 256 + threadIdx.x;
  float s = 0.f;
  #pragma unroll 8
  for (int st = 0; st < 64; ++st) s += part[(size_t)st * 16384 + f];
  out[f] = s;
}

extern "C" void kernel_launch(void* const* d_in, const int* in_sizes, int n_in,
                              void* d_out, int out_size, void* d_ws, size_t ws_size,
                              hipStream_t stream) {
  const float* inp  = (const float*)d_in[0];   // (512,32,2048) f32
  const float* msk  = (const float*)d_in[1];   // (512,32,2048) f32
  const float* Wt   = (const float*)d_in[2];   // (2048,32,32)  f32
  const float* bias = (const float*)d_in[3];   // (2048,32)     f32
  float* out = (float*)d_out;                  // (512,32)      f32

  const size_t part_sz = (size_t)64 * 16384 * sizeof(float);           // 4 MB
  const size_t wbf_sz  = (size_t)2048 * 1024 * sizeof(unsigned short); // 4 MB

  if (ws_size >= part_sz + wbf_sz) {
    float* part = (float*)d_ws;
    unsigned short* Wbf = (unsigned short*)((char*)d_ws + part_sz);
    wbf_prep<<<dim3(2048), dim3(256), 0, stream>>>(Wt, Wbf);
    attn_fused<true, true><<<dim3(1024), dim3(512), 0, stream>>>(
        inp, msk, Wt, Wbf, bias, part, out);
    reduce_part<<<dim3(64), dim3(256), 0, stream>>>(part, out);
  } else if (ws_size >= part_sz) {
    float* part = (float*)d_ws;
    attn_fused<false, true><<<dim3(1024), dim3(512), 0, stream>>>(
        inp, msk, Wt, nullptr, bias, part, out);
    reduce_part<<<dim3(64), dim3(256), 0, stream>>>(part, out);
  } else {
    (void)hipMemsetAsync(out, 0, (size_t)out_size * sizeof(float), stream);
    attn_fused<false, false><<<dim3(1024), dim3(512), 0, stream>>>(
        inp, msk, Wt, nullptr, bias, nullptr, out);
  }
}

// Round 11
// 279.870 us; speedup vs baseline: 1.2426x; 1.0235x over previous
//
#include <hip/hip_runtime.h>

#define EPS_K 1e-7f

typedef __attribute__((ext_vector_type(8)))  short          frag8;  // 8 bf16 (4 VGPRs)
typedef __attribute__((ext_vector_type(4)))  float          accf4;  // 16x16 MFMA C/D
typedef __attribute__((ext_vector_type(4)))  unsigned short us4;    // 8B LDS read
typedef __attribute__((ext_vector_type(4)))  float          f32x4;

__device__ __forceinline__ unsigned f2bf(float f) {
  union { float f; unsigned u; } v; v.f = f;
  unsigned u = v.u;
  u += 0x7FFFu + ((u >> 16) & 1u);   // RNE
  return u >> 16;
}
__device__ __forceinline__ float bf2f(unsigned short s) {
  union { unsigned u; float f; } v; v.u = ((unsigned)s) << 16;
  return v.f;
}
__device__ __forceinline__ unsigned pk_bf16(float lo, float hi) {
  return f2bf(lo) | (f2bf(hi) << 16);
}
// streaming (no-allocate) load — R8-proven (+27%); compiler-scheduled (R9:
// manual pinning regresses).
__device__ __forceinline__ f32x4 ld_nt(const float* p) {
  return __builtin_nontemporal_load((const f32x4*)p);
}

// ---------------------------------------------------------------------------
// Pre-pass: W (2048,32,32) f32 [s][t][u]  ->  Wbf bf16 [s][u][t] (4 MB in ws)
// (verified, unchanged since round 0)
// ---------------------------------------------------------------------------
__global__ __launch_bounds__(256) void wbf_prep(
    const float* __restrict__ Wt, unsigned short* __restrict__ Wbf)
{
  __shared__ unsigned short tile[32 * 33];     // [t][u], pad 33
  const int s   = blockIdx.x;
  const int tid = threadIdx.x;
  {
    const int t  = tid >> 3;
    const int uc = tid & 7;                    // u-chunk of 4
    const float4 v = *(const float4*)(Wt + s * 1024 + t * 32 + 4 * uc);
    tile[t * 33 + 4 * uc + 0] = (unsigned short)f2bf(v.x);
    tile[t * 33 + 4 * uc + 1] = (unsigned short)f2bf(v.y);
    tile[t * 33 + 4 * uc + 2] = (unsigned short)f2bf(v.z);
    tile[t * 33 + 4 * uc + 3] = (unsigned short)f2bf(v.w);
  }
  __syncthreads();
  {
    const int u  = tid >> 3;
    const int tc = tid & 7;                    // t-chunk of 4
    uint2 d;
    d.x = (unsigned)tile[(4 * tc + 0) * 33 + u] | ((unsigned)tile[(4 * tc + 1) * 33 + u] << 16);
    d.y = (unsigned)tile[(4 * tc + 2) * 33 + u] | ((unsigned)tile[(4 * tc + 3) * 33 + u] << 16);
    *(uint2*)(Wbf + s * 1024 + u * 32 + 4 * tc) = d;  // lanes tc -> 64B contig
  }
}

// ---------------------------------------------------------------------------
// Main kernel: 256-B-chunk staging (granularity ladder 64->128->256 B) while
// KEEPING 2 blocks/CU overlap, via 16x16x32 MFMA (16-b tiles).
//
// Tile: 16 b x 64 s x 32 t, LDS 64 KB. Grid 1024 = 32 bg x 32 st
// (st = blockIdx&31 -> first resident generation covers ALL st of bg 0..15
// = full 8-KB rows aggregated across the concurrent cohort).
// 512 thr (8 waves), 2 blocks/CU, 4 blocks/CU over 2 generations.
//
// Staging thread-map (bank-verified): sc = tid&15 (16 lanes x 16 B = 256-B
// contiguous per (b,t) row), bl = (tid>>4)&3, hi = tid>>6:
// b = (hi&3)*4 + bl, tb = (hi>>2)|(it<<1). A wave carries 4 b-values ->
// XOR keys (4sc+w)&7 ^ (b&7) span all 8 bank groups (no R5-style 32-way).
//
// x-tile LDS: per-b 2048 ush; chunk L = (t>>3)*64 + s_loc (8 t per chunk),
// swizzle L ^ (b&7)  (64 === 0 mod 8 -> verified R0 bank identity).
//
// MFMA 16x16x32 bf16 (fragment family pattern; C/D layout HW-verified
// m89/m91: col=lane&15, row=(lane>>4)*4+reg):
//   A[m=u][k=t]: m = lane&15, k = (lane>>4)*8+j  (a1: u 0..15, a2: u 16..31)
//   B[k=t][n=b]: n = lane&15, k = (lane>>4)*8+j  (one frag, shared)
// Per wave: sl = wv*8+si (8 si). Softmax sum: shfl_xor 16 then 32.
// ---------------------------------------------------------------------------
template <bool USE_WS>
__global__ __launch_bounds__(512, 4) void attn_fused(
    const float* __restrict__ inp,
    const float* __restrict__ msk,
    const unsigned short* __restrict__ Wbf,
    const float* __restrict__ bias,
    float* __restrict__ part,
    float* __restrict__ out)
{
  __shared__ unsigned short x_us[16 * 2048];   // 64 KB

  const int tid = threadIdx.x;
  const int st  = blockIdx.x & 31;             // s-tile 0..31 (64 s each)
  const int bg  = blockIdx.x >> 5;             // b-group 0..31 (16 b each)
  const int s0  = st * 64;

  // ---- stage x = inp*msk: 256-B contiguous per (b,t) row ----
  const int sc = tid & 15;                     // s-quad 0..15 -> 64 s
  const int bl = (tid >> 4) & 3;
  const int hi = tid >> 6;
  const int b_s = (hi & 3) * 4 + bl;           // 0..15
  #pragma unroll
  for (int it = 0; it < 2; ++it) {
    const int tb = (hi >> 2) | (it << 1);      // t-block of 8: 0..3
    const float* ip = inp + ((size_t)(bg * 16 + b_s) * 32 + 8 * tb) * 2048 + s0 + 4 * sc;
    const float* mp = msk + ((size_t)(bg * 16 + b_s) * 32 + 8 * tb) * 2048 + s0 + 4 * sc;
    f32x4 vi[8], vm[8];
    #pragma unroll
    for (int r = 0; r < 8; ++r) {              // t = 8*tb + r
      vi[r] = ld_nt(ip + r * 2048);
      vm[r] = ld_nt(mp + r * 2048);
    }
    #pragma unroll
    for (int w = 0; w < 4; ++w) {              // s_loc = 4*sc + w
      const int L = tb * 64 + 4 * sc + w;      // chunk 0..255
      uint4 d;
      d.x = pk_bf16(vi[0][w] * vm[0][w], vi[1][w] * vm[1][w]);
      d.y = pk_bf16(vi[2][w] * vm[2][w], vi[3][w] * vm[3][w]);
      d.z = pk_bf16(vi[4][w] * vm[4][w], vi[5][w] * vm[5][w]);
      d.w = pk_bf16(vi[6][w] * vm[6][w], vi[7][w] * vm[7][w]);
      *(uint4*)(x_us + b_s * 2048 + ((L ^ (b_s & 7)) * 8)) = d;
    }
  }
  __syncthreads();

  const int lane = tid & 63;
  const int wv   = tid >> 6;                   // wave 0..7
  const int n16  = lane & 15;                  // b (B col) / u-low (A row)
  const int kg   = lane >> 4;                  // 0..3: k-group (t = kg*8+j)
  const int nx   = n16 & 7;
  const int kg2  = kg >> 1, kw = kg & 1;

  float O1[4], O2[4];
  #pragma unroll
  for (int i = 0; i < 4; ++i) { O1[i] = 0.f; O2[i] = 0.f; }

  #pragma unroll
  for (int si = 0; si < 8; ++si) {
    const int sl = wv * 8 + si;                // 0..63
    const int s  = s0 + sl;

    // A-frags from Wbf[s][u][t]: u = n16 (+16), t = kg*8..+7 (16 B contig)
    const frag8 a1 = *(const frag8*)(Wbf + (size_t)s * 1024 + n16 * 32 + kg * 8);
    const frag8 a2 = *(const frag8*)(Wbf + (size_t)s * 1024 + (16 + n16) * 32 + kg * 8);
    // B-frag: b = n16, t = kg*8..+7 -> chunk kg*64 + sl
    const frag8 bf = *(const frag8*)(x_us + n16 * 2048 + (((kg * 64 + sl) ^ nx) * 8));

    // bias -> acc init: row u = kg*4 + reg (+16)
    accf4 acc1, acc2;
    {
      const f32x4 bb1 = *(const f32x4*)(bias + s * 32 + kg * 4);
      const f32x4 bb2 = *(const f32x4*)(bias + s * 32 + 16 + kg * 4);
      acc1[0] = bb1[0]; acc1[1] = bb1[1]; acc1[2] = bb1[2]; acc1[3] = bb1[3];
      acc2[0] = bb2[0]; acc2[1] = bb2[1]; acc2[2] = bb2[2]; acc2[3] = bb2[3];
    }
    acc1 = __builtin_amdgcn_mfma_f32_16x16x32_bf16(a1, bf, acc1, 0, 0, 0);
    acc2 = __builtin_amdgcn_mfma_f32_16x16x32_bf16(a2, bf, acc2, 0, 0, 0);

    // e = exp(tanh(z)); tanh(z) = 1 - 2/(exp(2z)+1)   (verified math)
    float e1[4], e2[4];
    float ps = 0.f;
    #pragma unroll
    for (int i = 0; i < 4; ++i) {
      const float za = acc1[i], zb = acc2[i];
      const float ea = __expf(2.f * za), eb = __expf(2.f * zb);
      e1[i] = __expf(1.f - 2.f / (ea + 1.f));
      e2[i] = __expf(1.f - 2.f / (eb + 1.f));
      ps += e1[i] + e2[i];
    }
    // sum over all 32 u for fixed b: reduce across lane bits 4,5
    float t1  = ps + __shfl_xor(ps, 16, 64);
    const float tot = t1 + __shfl_xor(t1, 32, 64);
    const float inv = 1.f / (tot + EPS_K);

    // O += att * x : u = kg*4+i (+16) -> chunk (u>>3)*64+sl, elem 4*kw+i
    const us4 xv1 = *(const us4*)(x_us + n16 * 2048 + (((kg2 * 64 + sl) ^ nx) * 8) + 4 * kw);
    const us4 xv2 = *(const us4*)(x_us + n16 * 2048 + ((((2 + kg2) * 64 + sl) ^ nx) * 8) + 4 * kw);
    #pragma unroll
    for (int i = 0; i < 4; ++i) {
      O1[i] += e1[i] * inv * bf2f(xv1[i]);
      O2[i] += e2[i] * inv * bf2f(xv2[i]);
    }
  }

  // ---- cross-wave reduction in LDS (8 waves x 512 f32 = 16 KB, reuse) ----
  __syncthreads();
  float* red = (float*)x_us;
  #pragma unroll
  for (int i = 0; i < 4; ++i) {
    const int u1 = kg * 4 + i;
    const int u2 = 16 + kg * 4 + i;
    red[wv * 512 + n16 * 32 + (u1 ^ n16)] = O1[i];
    red[wv * 512 + n16 * 32 + (u2 ^ n16)] = O2[i];
  }
  __syncthreads();

  const int q  = tid;                          // 512 outputs: b' = q>>5, u = q&31
  const int bq = q >> 5, uq = q & 31;
  float sum = 0.f;
  #pragma unroll
  for (int w = 0; w < 8; ++w) sum += red[w * 512 + bq * 32 + (uq ^ bq)];
  if (USE_WS) {
    part[(size_t)st * 16384 + bg * 512 + q] = sum;
  } else {
    atomicAdd(out + bg * 512 + q, sum);
  }
}

// out[f] = sum over 32 s-tiles of part[st][f]
__global__ __launch_bounds__(256) void reduce_part(
    const float* __restrict__ part, float* __restrict__ out)
{
  const int f = blockIdx.x * 256 + threadIdx.x;
  float s = 0.f;
  #pragma unroll 8
  for (int st = 0; st < 32; ++st) s += part[(size_t)st * 16384 + f];
  out[f] = s;
}

// ---------------------------------------------------------------------------
// Safety fallback (ws too small): correct, slow, f32-precise.
// ---------------------------------------------------------------------------
__global__ __launch_bounds__(256) void attn_naive(
    const float* __restrict__ inp, const float* __restrict__ msk,
    const float* __restrict__ Wt, const float* __restrict__ bias,
    float* __restrict__ out)
{
  const int idx = blockIdx.x * 256 + threadIdx.x;  // 0..16383
  const int b = idx >> 5, sc = idx & 31;
  float O[32];
  #pragma unroll
  for (int u = 0; u < 32; ++u) O[u] = 0.f;
  for (int si = 0; si < 64; ++si) {
    const int s = sc * 64 + si;
    float x[32], z[32];
    for (int t = 0; t < 32; ++t) {
      x[t] = inp[((size_t)b * 32 + t) * 2048 + s] * msk[((size_t)b * 32 + t) * 2048 + s];
      z[t] = bias[s * 32 + t];
    }
    for (int t = 0; t < 32; ++t) {
      const float xv = x[t];
      for (int u = 0; u < 32; ++u) z[u] += xv * Wt[(size_t)s * 1024 + t * 32 + u];
    }
    float e[32], ps = 0.f;
    for (int u = 0; u < 32; ++u) { e[u] = expf(tanhf(z[u])); ps += e[u]; }
    const float inv = 1.f / (ps + EPS_K);
    for (int u = 0; u < 32; ++u) O[u] += e[u] * inv * x[u];
  }
  for (int u = 0; u < 32; ++u) atomicAdd(out + b * 32 + u, O[u]);
}

extern "C" void kernel_launch(void* const* d_in, const int* in_sizes, int n_in,
                              void* d_out, int out_size, void* d_ws, size_t ws_size,
                              hipStream_t stream) {
  const float* inp  = (const float*)d_in[0];   // (512,32,2048) f32
  const float* msk  = (const float*)d_in[1];   // (512,32,2048) f32
  const float* Wt   = (const float*)d_in[2];   // (2048,32,32)  f32
  const float* bias = (const float*)d_in[3];   // (2048,32)     f32
  float* out = (float*)d_out;                  // (512,32)      f32

  const size_t part_sz = (size_t)32 * 16384 * sizeof(float);           // 2 MB
  const size_t wbf_sz  = (size_t)2048 * 1024 * sizeof(unsigned short); // 4 MB

  if (ws_size >= part_sz + wbf_sz) {
    float* part = (float*)d_ws;
    unsigned short* Wbf = (unsigned short*)((char*)d_ws + part_sz);
    wbf_prep<<<dim3(2048), dim3(256), 0, stream>>>(Wt, Wbf);
    attn_fused<true><<<dim3(1024), dim3(512), 0, stream>>>(
        inp, msk, Wbf, bias, part, out);
    reduce_part<<<dim3(64), dim3(256), 0, stream>>>(part, out);
  } else if (ws_size >= wbf_sz) {
    unsigned short* Wbf = (unsigned short*)d_ws;
    (void)hipMemsetAsync(out, 0, (size_t)out_size * sizeof(float), stream);
    wbf_prep<<<dim3(2048), dim3(256), 0, stream>>>(Wt, Wbf);
    attn_fused<false><<<dim3(1024), dim3(512), 0, stream>>>(
        inp, msk, Wbf, bias, nullptr, out);
  } else {
    (void)hipMemsetAsync(out, 0, (size_t)out_size * sizeof(float), stream);
    attn_naive<<<dim3(64), dim3(256), 0, stream>>>(inp, msk, Wt, bias, out);
  }
}